// Round 6
// baseline (114.633 us; speedup 1.0000x reference)
//
#include <hip/hip_runtime.h>
#include <hip/hip_bf16.h>

#define NPOS (4*16*64*64)             // 262144 positions
#define KCODES 512
#define CDIM 64
#define OUT_SCALAR_IDX ((size_t)NPOS * CDIM)

// d_ws layout
#define WS_GCOUNT 0                   // 512 * int (used-flags)
#define WS_EMB    4096                // 64 KB: row-major (-2*e) bf16 image, 128 B/row
#define WS_EE     (4096 + 65536)      // 512 * float: ||e||^2 + 1.0 bias

typedef short short8 __attribute__((ext_vector_type(8)));
typedef float f32x4 __attribute__((ext_vector_type(4)));

__device__ __forceinline__ ushort f2bf(float f) {
  uint u = __builtin_bit_cast(uint, f);
  u += 0x7fff + ((u >> 16) & 1);        // RNE
  return (ushort)(u >> 16);
}

// ---- prep: codebook -> -2x bf16 image + biased ee + zero flags ----
__global__ __launch_bounds__(64) void vq_prep(
    const float* __restrict__ emb, char* __restrict__ ws) {
  const int r = blockIdx.x * 64 + threadIdx.x;     // 8 x 64 = 512 rows
  ((int*)(ws + WS_GCOUNT))[r] = 0;
  const float4* er = (const float4*)(emb + r * CDIM);
  char* img = ws + WS_EMB;
  float ee = 0.f;
  #pragma unroll
  for (int q = 0; q < 8; ++q) {
    float4 x = er[2 * q], y = er[2 * q + 1];
    ee = fmaf(x.x, x.x, ee); ee = fmaf(x.y, x.y, ee);
    ee = fmaf(x.z, x.z, ee); ee = fmaf(x.w, x.w, ee);
    ee = fmaf(y.x, y.x, ee); ee = fmaf(y.y, y.y, ee);
    ee = fmaf(y.z, y.z, ee); ee = fmaf(y.w, y.w, ee);
    uint4 ch;
    ch.x = f2bf(-2.f * x.x) | ((uint)f2bf(-2.f * x.y) << 16);
    ch.y = f2bf(-2.f * x.z) | ((uint)f2bf(-2.f * x.w) << 16);
    ch.z = f2bf(-2.f * y.x) | ((uint)f2bf(-2.f * y.y) << 16);
    ch.w = f2bf(-2.f * y.z) | ((uint)f2bf(-2.f * y.w) << 16);
    *(uint4*)(img + r * 128 + q * 16) = ch;
  }
  ((float*)(ws + WS_EE))[r] = ee + 1.0f;   // bias -> distances ~1.0, uint-monotone
}

__device__ __forceinline__ uint pk2(float a, float b) {
  __hip_bfloat162 h = __float22bfloat162_rn(make_float2(a, b));  // v_cvt_pk_bf16_f32
  uint u;
  __builtin_memcpy(&u, &h, sizeof(u));
  return u;
}

__global__ __launch_bounds__(256, 4) void vq_mfma(
    const float* __restrict__ z, const float* __restrict__ emb,
    const char* __restrict__ ws, float* __restrict__ out,
    int* __restrict__ gflags) {
  __shared__ uint s_wkey[4][256];     // per-wave per-row min keys (4 KB)
  __shared__ int s_hist[KCODES];      // 2 KB

  const int tid = threadIdx.x;
  const int lane = tid & 63;
  const int w = tid >> 6;             // wave id = code quarter
  const int col = lane & 15;
  const int kg = lane >> 4;

  s_hist[tid] = 0;
  s_hist[tid + 256] = 0;

  // ---- B resident in registers: this wave's 128 codes (8 tiles x K=64) ----
  const char* img = ws + WS_EMB + w * 16384;      // 128 rows x 128 B
  const float* eeq = (const float*)(ws + WS_EE) + w * 128;
  const int boff = col * 128 + kg * 16;
  short8 bfr[8][2];
  float eet[8];
  #pragma unroll
  for (int t = 0; t < 8; ++t) {
    bfr[t][0] = *(const short8*)(img + t * 2048 + boff);
    bfr[t][1] = *(const short8*)(img + t * 2048 + boff + 64);
    eet[t] = eeq[t * 16 + col];
  }

  const int nb = blockIdx.x * 256;
  const int b = nb >> 16, spb = nb & 65535;       // single batch per block
  const float* zp = z + ((size_t)b << 22) + spb;
  float* op = out + ((size_t)b << 22) + spb;

  // ---- A prefetch (one row-tile ahead) ----
  float pf[16];
  #pragma unroll
  for (int h = 0; h < 2; ++h)
    #pragma unroll
    for (int j = 0; j < 8; ++j)
      pf[h * 8 + j] = zp[((size_t)(h * 32 + kg * 8 + j) << 16) + col];  // rt=0

  #pragma unroll 2
  for (int rt = 0; rt < 16; ++rt) {
    // convert current A tile to bf16 fragments
    uint4 u0, u1;
    u0.x = pk2(pf[0], pf[1]);  u0.y = pk2(pf[2], pf[3]);
    u0.z = pk2(pf[4], pf[5]);  u0.w = pk2(pf[6], pf[7]);
    u1.x = pk2(pf[8], pf[9]);  u1.y = pk2(pf[10], pf[11]);
    u1.z = pk2(pf[12], pf[13]); u1.w = pk2(pf[14], pf[15]);
    const short8 a0 = __builtin_bit_cast(short8, u0);
    const short8 a1 = __builtin_bit_cast(short8, u1);

    // issue next tile's A loads (wrap: harmless reload of rt 0)
    {
      const int nrt = (rt + 1) & 15;
      #pragma unroll
      for (int h = 0; h < 2; ++h)
        #pragma unroll
        for (int j = 0; j < 8; ++j)
          pf[h * 8 + j] = zp[((size_t)(h * 32 + kg * 8 + j) << 16) + nrt * 16 + col];
    }

    uint key[4] = {0xFFFFFFFFu, 0xFFFFFFFFu, 0xFFFFFFFFu, 0xFFFFFFFFu};
    #pragma unroll
    for (int t = 0; t < 8; ++t) {
      const f32x4 cin = {eet[t], eet[t], eet[t], eet[t]};   // 1 + ||e||^2
      f32x4 acc = __builtin_amdgcn_mfma_f32_16x16x32_bf16(a0, bfr[t][0], cin, 0, 0, 0);
      acc = __builtin_amdgcn_mfma_f32_16x16x32_bf16(a1, bfr[t][1], acc, 0, 0, 0);
      const uint g = (uint)(w * 8 + t);                     // global tile id, 5 bits
      #pragma unroll
      for (int s = 0; s < 4; ++s) {
        uint kb = (__builtin_bit_cast(uint, acc[s]) & 0xFFFFFFE0u) | g;
        key[s] = kb < key[s] ? kb : key[s];
      }
    }

    // per-row argmin across 16 cols, then per-wave key -> LDS
    #pragma unroll
    for (int s = 0; s < 4; ++s) {
      uint k = (key[s] << 4) | (uint)col;   // (dist, tile, col) lex order
      #pragma unroll
      for (int m = 1; m < 16; m <<= 1) {
        uint o = (uint)__shfl_xor((int)k, m, 64);
        k = o < k ? o : k;
      }
      if (col == 0) s_wkey[w][rt * 16 + kg * 4 + s] = k;
    }
  }
  __syncthreads();

  // ---- cross-wave min + exact fp32 gather + coalesced strided write ----
  uint k = s_wkey[0][tid];
  {
    uint k1 = s_wkey[1][tid], k2 = s_wkey[2][tid], k3 = s_wkey[3][tid];
    k = k1 < k ? k1 : k;  k = k2 < k ? k2 : k;  k = k3 < k ? k3 : k;
  }
  const int myidx = (int)(((k >> 4) & 31u) * 16u + (k & 15u));
  atomicAdd(&s_hist[myidx], 1);
  {
    const float4* ef = (const float4*)(emb + myidx * CDIM);
    float* o = op + tid;
    #pragma unroll
    for (int q = 0; q < 16; ++q) {
      float4 e4 = ef[q];
      o[(size_t)(4 * q + 0) << 16] = e4.x;
      o[(size_t)(4 * q + 1) << 16] = e4.y;
      o[(size_t)(4 * q + 2) << 16] = e4.z;
      o[(size_t)(4 * q + 3) << 16] = e4.w;
    }
  }
  __syncthreads();
  if (s_hist[tid]) gflags[tid] = 1;              // idempotent used-flags
  if (s_hist[tid + 256]) gflags[tid + 256] = 1;
}

__global__ __launch_bounds__(512) void vq_count(
    const int* __restrict__ gflags, float* __restrict__ out) {
  __shared__ int red[512];
  const int t = threadIdx.x;
  red[t] = (gflags[t] > 0) ? 1 : 0;
  __syncthreads();
  for (int s = 256; s > 0; s >>= 1) {
    if (t < s) red[t] += red[t + s];
    __syncthreads();
  }
  if (t == 0) out[OUT_SCALAR_IDX] = (float)red[0];
}

extern "C" void kernel_launch(void* const* d_in, const int* in_sizes, int n_in,
                              void* d_out, int out_size, void* d_ws, size_t ws_size,
                              hipStream_t stream) {
  const float* z = (const float*)d_in[0];
  const float* emb = (const float*)d_in[1];
  float* out = (float*)d_out;
  char* ws = (char*)d_ws;
  int* gflags = (int*)(ws + WS_GCOUNT);

  vq_prep<<<8, 64, 0, stream>>>(emb, ws);
  vq_mfma<<<NPOS / 256, 256, 0, stream>>>(z, emb, ws, out, gflags);
  vq_count<<<1, 512, 0, stream>>>(gflags, out);
}

// Round 7
// 43.473 us; speedup vs baseline: 2.6369x; 2.6369x over previous
//
#include <hip/hip_runtime.h>
#include <hip/hip_bf16.h>

#define NPOS (4*16*64*64)             // 262144 positions
#define KCODES 512
#define CDIM 64
#define OUT_SCALAR_IDX ((size_t)NPOS * CDIM)

// d_ws layout
#define WS_GCOUNT 0                   // 512 * int (used-flags)
#define WS_EMB    4096                // 64 KB: pre-SWIZZLED (-2*e) bf16 image
#define WS_EE     (4096 + 65536)      // 512 * float: ||e||^2 + 1.0 bias

typedef short short8 __attribute__((ext_vector_type(8)));
typedef float f32x4 __attribute__((ext_vector_type(4)));

__device__ __forceinline__ ushort f2bf(float f) {
  uint u = __builtin_bit_cast(uint, f);
  u += 0x7fff + ((u >> 16) & 1);        // RNE
  return (ushort)(u >> 16);
}

// ---- prep: codebook -> swizzled -2x bf16 image + biased ee + zero flags ----
__global__ __launch_bounds__(64) void vq_prep(
    const float* __restrict__ emb, char* __restrict__ ws) {
  const int r = blockIdx.x * 64 + threadIdx.x;     // 8 x 64 = 512 rows
  ((int*)(ws + WS_GCOUNT))[r] = 0;
  const float4* er = (const float4*)(emb + r * CDIM);
  char* img = ws + WS_EMB;
  float ee = 0.f;
  #pragma unroll
  for (int q = 0; q < 8; ++q) {
    float4 x = er[2 * q], y = er[2 * q + 1];
    ee = fmaf(x.x, x.x, ee); ee = fmaf(x.y, x.y, ee);
    ee = fmaf(x.z, x.z, ee); ee = fmaf(x.w, x.w, ee);
    ee = fmaf(y.x, y.x, ee); ee = fmaf(y.y, y.y, ee);
    ee = fmaf(y.z, y.z, ee); ee = fmaf(y.w, y.w, ee);
    uint4 ch;
    ch.x = f2bf(-2.f * x.x) | ((uint)f2bf(-2.f * x.y) << 16);
    ch.y = f2bf(-2.f * x.z) | ((uint)f2bf(-2.f * x.w) << 16);
    ch.z = f2bf(-2.f * y.x) | ((uint)f2bf(-2.f * y.y) << 16);
    ch.w = f2bf(-2.f * y.z) | ((uint)f2bf(-2.f * y.w) << 16);
    *(uint4*)(img + ((r * 128 + q * 16) ^ ((r & 7) << 4))) = ch;  // XOR-swizzled
  }
  ((float*)(ws + WS_EE))[r] = ee + 1.0f;   // bias -> distances ~1.0, uint-monotone
}

__device__ __forceinline__ uint pk2(float a, float b) {
  __hip_bfloat162 h = __float22bfloat162_rn(make_float2(a, b));  // v_cvt_pk_bf16_f32
  uint u;
  __builtin_memcpy(&u, &h, sizeof(u));
  return u;
}

__global__ __launch_bounds__(512, 4) void vq_mfma(
    const float* __restrict__ z, const float* __restrict__ emb,
    const char* __restrict__ ws, float* __restrict__ out,
    int* __restrict__ gflags) {
  __shared__ ushort embs[KCODES * CDIM];   // 64 KB swizzled -2x bf16
  __shared__ float s_ee[KCODES];           // 2 KB
  __shared__ uint s_idx[512];              // 2 KB
  __shared__ int s_hist[KCODES];           // 2 KB

  const int tid = threadIdx.x;
  const int lane = tid & 63;
  const int w = tid >> 6;                  // 8 waves
  const int col = lane & 15;
  const int kg = lane >> 4;

  // ---- DMA issue order: ee (oldest) -> half1 -> A loads -> half2 (newest) ----
  if (tid < 128)
    __builtin_amdgcn_global_load_lds(
        (const __attribute__((address_space(1))) void*)(ws + WS_EE + tid * 16),
        (__attribute__((address_space(3))) void*)((char*)s_ee + tid * 16), 16, 0, 0);
  const char* src = ws + WS_EMB;
  #pragma unroll
  for (int i = 0; i < 4; ++i) {            // half1: embs bytes [0, 32768)
    const int off = (i * 512 + tid) * 16;
    __builtin_amdgcn_global_load_lds(
        (const __attribute__((address_space(1))) void*)(src + off),
        (__attribute__((address_space(3))) void*)((char*)embs + off), 16, 0, 0);
  }

  // ---- A fragments: 4 row-tiles x 2 K-halves (loads overlap the DMA) ----
  short8 af[4][2];
  const int nb = blockIdx.x * 512;
  const int b = nb >> 16, spb = nb & 65535;     // 512 | 65536 -> single batch
  const float* zp0 = z + ((size_t)b << 22) + spb;
  #pragma unroll
  for (int rt = 0; rt < 4; ++rt) {
    const float* zp = zp0 + w * 64 + rt * 16 + col;
    #pragma unroll
    for (int h = 0; h < 2; ++h) {
      float v[8];
      #pragma unroll
      for (int j = 0; j < 8; ++j)
        v[j] = zp[(size_t)(h * 32 + kg * 8 + j) << 16];
      uint4 u;
      u.x = pk2(v[0], v[1]); u.y = pk2(v[2], v[3]);
      u.z = pk2(v[4], v[5]); u.w = pk2(v[6], v[7]);
      af[rt][h] = __builtin_bit_cast(short8, u);
    }
  }

  #pragma unroll
  for (int i = 4; i < 8; ++i) {            // half2: embs bytes [32768, 65536)
    const int off = (i * 512 + tid) * 16;
    __builtin_amdgcn_global_load_lds(
        (const __attribute__((address_space(1))) void*)(src + off),
        (__attribute__((address_space(3))) void*)((char*)embs + off), 16, 0, 0);
  }
  s_hist[tid] = 0;

  // all but half2 (4 newest VMEM) drained; hist-zero visible
  asm volatile("s_waitcnt vmcnt(4) lgkmcnt(0)" ::: "memory");
  __builtin_amdgcn_sched_barrier(0);
  __builtin_amdgcn_s_barrier();
  __builtin_amdgcn_sched_barrier(0);

  // ---- hot loop: 2 halves x 16 code-tiles, depth-2 B prefetch ----
  uint key[4][4];
  #pragma unroll
  for (int rt = 0; rt < 4; ++rt)
    #pragma unroll
    for (int s = 0; s < 4; ++s) key[rt][s] = 0xFFFFFFFFu;

  const int swz = (lane & 7) << 4;
  const int lbase = col * 128 + kg * 16;

#define HALF_LOOP(C0)                                                          \
  {                                                                            \
    int ct = (C0);                                                             \
    const char* p = (const char*)embs + ct * 2048;                             \
    short8 b0 = *(const short8*)(p + (lbase ^ swz));                           \
    short8 b1 = *(const short8*)(p + ((lbase + 64) ^ swz));                    \
    float eev = s_ee[ct * 16 + col];                                           \
    _Pragma("unroll 4")                                                        \
    for (int i = 0; i < 16; ++i) {                                             \
      const short8 c0r = b0, c1r = b1;                                        \
      const float ec = eev;                                                    \
      const uint ctv = (uint)ct;                                               \
      const int nct = (C0) + ((i + 1) & 15);                                   \
      const char* np = (const char*)embs + nct * 2048;                         \
      b0 = *(const short8*)(np + (lbase ^ swz));                               \
      b1 = *(const short8*)(np + ((lbase + 64) ^ swz));                        \
      eev = s_ee[nct * 16 + col];                                              \
      const f32x4 cin = {ec, ec, ec, ec};                                      \
      _Pragma("unroll")                                                        \
      for (int rt = 0; rt < 4; ++rt) {                                         \
        f32x4 acc =                                                            \
            __builtin_amdgcn_mfma_f32_16x16x32_bf16(af[rt][0], c0r, cin, 0, 0, 0); \
        acc = __builtin_amdgcn_mfma_f32_16x16x32_bf16(af[rt][1], c1r, acc, 0, 0, 0); \
        _Pragma("unroll")                                                      \
        for (int s = 0; s < 4; ++s) {                                          \
          uint kb = (__builtin_bit_cast(uint, acc[s]) & 0xFFFFFFE0u) | ctv;    \
          key[rt][s] = kb < key[rt][s] ? kb : key[rt][s];                      \
        }                                                                      \
      }                                                                        \
      ct = nct;                                                                \
    }                                                                          \
  }

  HALF_LOOP(0)

  asm volatile("s_waitcnt vmcnt(0)" ::: "memory");   // half2 arrived
  __builtin_amdgcn_sched_barrier(0);
  __builtin_amdgcn_s_barrier();
  __builtin_amdgcn_sched_barrier(0);

  HALF_LOOP(16)

  // ---- per-row argmin across 16 cols: pure uint-min butterfly ----
  #pragma unroll
  for (int rt = 0; rt < 4; ++rt) {
    #pragma unroll
    for (int s = 0; s < 4; ++s) {
      uint k = (key[rt][s] << 4) | (uint)col;   // (dist, ct, col) lex order
      #pragma unroll
      for (int m = 1; m < 16; m <<= 1) {
        uint o = (uint)__shfl_xor((int)k, m, 64);
        k = o < k ? o : k;
      }
      if (col == 0) s_idx[w * 64 + rt * 16 + kg * 4 + s] = k;
    }
  }
  __syncthreads();

  // ---- epilogue: exact fp32 emb gather (L2-hot) + coalesced strided write ----
  const uint kk = s_idx[tid];
  const int myidx = (int)(((kk >> 4) & 31u) * 16u + (kk & 15u));
  atomicAdd(&s_hist[myidx], 1);
  {
    const float4* ef = (const float4*)(emb + myidx * CDIM);
    float* o = out + ((size_t)b << 22) + spb + tid;
    #pragma unroll
    for (int q = 0; q < 16; ++q) {
      float4 e4 = ef[q];
      o[(size_t)(4 * q + 0) << 16] = e4.x;
      o[(size_t)(4 * q + 1) << 16] = e4.y;
      o[(size_t)(4 * q + 2) << 16] = e4.z;
      o[(size_t)(4 * q + 3) << 16] = e4.w;
    }
  }
  __syncthreads();
  if (s_hist[tid]) gflags[tid] = 1;              // idempotent used-flags
}

__global__ __launch_bounds__(512) void vq_count(
    const int* __restrict__ gflags, float* __restrict__ out) {
  __shared__ int red[512];
  const int t = threadIdx.x;
  red[t] = (gflags[t] > 0) ? 1 : 0;
  __syncthreads();
  for (int s = 256; s > 0; s >>= 1) {
    if (t < s) red[t] += red[t + s];
    __syncthreads();
  }
  if (t == 0) out[OUT_SCALAR_IDX] = (float)red[0];
}

extern "C" void kernel_launch(void* const* d_in, const int* in_sizes, int n_in,
                              void* d_out, int out_size, void* d_ws, size_t ws_size,
                              hipStream_t stream) {
  const float* z = (const float*)d_in[0];
  const float* emb = (const float*)d_in[1];
  float* out = (float*)d_out;
  char* ws = (char*)d_ws;
  int* gflags = (int*)(ws + WS_GCOUNT);

  vq_prep<<<8, 64, 0, stream>>>(emb, ws);
  vq_mfma<<<NPOS / 512, 512, 0, stream>>>(z, emb, ws, out, gflags);
  vq_count<<<1, 512, 0, stream>>>(gflags, out);
}